// Round 1
// 507.058 us; speedup vs baseline: 1.0687x; 1.0687x over previous
//
#include <hip/hip_runtime.h>
#include <hip/hip_bf16.h>
#include <stdint.h>

#define GEPS 1e-20f

typedef __bf16 bf16x8 __attribute__((ext_vector_type(8)));
typedef float  f32x4  __attribute__((ext_vector_type(4)));

typedef const __attribute__((address_space(1))) uint32_t* gptr32;
typedef __attribute__((address_space(3))) uint32_t* lptr32;

__device__ __forceinline__ void load_lds16(const void* g, void* l) {
    __builtin_amdgcn_global_load_lds((gptr32)g, (lptr32)l, 16, 0, 0);
}

__device__ __forceinline__ uint16_t f2bf(float v) {
    __hip_bfloat16 b = __float2bfloat16(v);
    return *(uint16_t*)&b;
}
__device__ __forceinline__ float bf2f(uint16_t b) {
    uint32_t u = (uint32_t)b << 16;
    return __builtin_bit_cast(float, u);
}

// hardware transcendentals: v_log_f32 = log2(x), v_exp_f32 = 2^x  (~1 ULP)
#define LN2   0.69314718056f
#define LOG2E 1.44269504089f
__device__ __forceinline__ float fast_log(float x) { return __builtin_amdgcn_logf(x) * LN2; }
__device__ __forceinline__ float fast_exp(float x) { return __builtin_amdgcn_exp2f(x * LOG2E); }
__device__ __forceinline__ float fast_exp2(float x) { return __builtin_amdgcn_exp2f(x); }
__device__ __forceinline__ float fast_rcp(float x)  { return __builtin_amdgcn_rcpf(x); }

__device__ __forceinline__ void store_val(uint16_t* C, size_t idx, float v) { C[idx] = f2bf(v); }
__device__ __forceinline__ void store_val(float* C, size_t idx, float v)    { C[idx] = v; }

// ---------------------------------------------------------------------------
// cast fp32 -> bf16, vectorized (n must be multiple of 4)
// ---------------------------------------------------------------------------
__global__ void cast_bf16(const float* __restrict__ in, uint16_t* __restrict__ out, int n) {
    int i = (blockIdx.x * blockDim.x + threadIdx.x) * 4;
    if (i < n) {
        float4 v = *(const float4*)(in + i);
        ushort4 o;
        o.x = f2bf(v.x); o.y = f2bf(v.y); o.z = f2bf(v.z); o.w = f2bf(v.w);
        *(ushort4*)(out + i) = o;
    }
}

// ---------------------------------------------------------------------------
// W (K x N, fp32, row-major) -> Wt (Npad x K, bf16, row-major), zero-pad n>=N
// ---------------------------------------------------------------------------
__global__ void transpose_cast(const float* __restrict__ W, uint16_t* __restrict__ Wt,
                               int K, int N, int Npad) {
    __shared__ float tile[64][65];
    const int k0 = blockIdx.y * 64, n0 = blockIdx.x * 64;
    const int tx = threadIdx.x & 63, ty = threadIdx.x >> 6;
    for (int r = ty; r < 64; r += 4) {
        int n = n0 + tx;
        tile[r][tx] = (n < N) ? W[(size_t)(k0 + r) * N + n] : 0.f;
    }
    __syncthreads();
    for (int r = ty; r < 64; r += 4) {
        Wt[(size_t)(n0 + r) * K + k0 + tx] = f2bf(tile[tx][r]);
    }
}

// ---------------------------------------------------------------------------
// C = act(A @ Bt^T + bias)
// A: M x K bf16 row-major.  Bt: Npad x K bf16 row-major.
// 128x128 tile, BK=32, 256 threads = 4 waves (2x2), 16x16x32 bf16 MFMA.
// ACT: 0=none, 1=ELU, 2=sigmoid.  SNG: also store fp32 singleton cols to sngl.
// XCD-aware remap: each of the 8 XCDs owns a contiguous slice of m-tiles and
// sweeps all n-tiles per m, so the A-tile is fetched once into that XCD's L2.
// ---------------------------------------------------------------------------
template<int ACT, typename OutT, bool SNG>
__global__ __launch_bounds__(256)
void gemm_bt(const uint16_t* __restrict__ A, const uint16_t* __restrict__ Bt,
             const float* __restrict__ bias, OutT* __restrict__ C,
             float* __restrict__ sngl,
             int K, int Nout, int ldc) {
    __shared__ __align__(16) uint16_t As[128 * 32];
    __shared__ __align__(16) uint16_t Bs[128 * 32];

    const int t    = threadIdx.x;
    const int wave = t >> 6, lane = t & 63;

    // ---- XCD-aware block remap (gridDim.y must be divisible by 8) ----
    const int nbx = gridDim.x;
    const int bid = blockIdx.y * nbx + blockIdx.x;
    const int xcd = bid & 7;
    const int s   = bid >> 3;
    const int nidx = s % nbx;
    const int midx = xcd * (gridDim.y >> 3) + s / nbx;

    const int m0 = midx * 128, n0 = nidx * 128;
    const int wm = (wave >> 1) * 64, wn = (wave & 1) * 64;
    const int quad = lane >> 4;
    const int qk   = quad * 8;
    const int r15  = lane & 15;

    f32x4 acc[4][4] = {};

    const uint16_t* Ag = A  + (size_t)m0 * K;
    const uint16_t* Bg = Bt + (size_t)n0 * K;

    for (int k0 = 0; k0 < K; k0 += 32) {
        __syncthreads();
        #pragma unroll
        for (int rd = 0; rd < 2; ++rd) {
            int c = t + rd * 256;            // 16B-chunk index, 0..511
            int row = c >> 2, kc = (c & 3) * 8;
            load_lds16(Ag + (size_t)row * K + k0 + kc, &As[c * 8]);
            load_lds16(Bg + (size_t)row * K + k0 + kc, &Bs[c * 8]);
        }
        __syncthreads();

        bf16x8 a[4], b[4];
        #pragma unroll
        for (int i = 0; i < 4; ++i)
            a[i] = *(const bf16x8*)&As[(wm + i * 16 + r15) * 32 + qk];
        #pragma unroll
        for (int i = 0; i < 4; ++i)
            b[i] = *(const bf16x8*)&Bs[(wn + i * 16 + r15) * 32 + qk];

        #pragma unroll
        for (int mi = 0; mi < 4; ++mi)
            #pragma unroll
            for (int ni = 0; ni < 4; ++ni)
                acc[mi][ni] = __builtin_amdgcn_mfma_f32_16x16x32_bf16(
                    a[mi], b[ni], acc[mi][ni], 0, 0, 0);
    }

    // epilogue: C/D layout col = lane&15, row = quad*4 + reg  [verified m89]
    #pragma unroll
    for (int ni = 0; ni < 4; ++ni) {
        int col = n0 + wn + ni * 16 + r15;
        if (col < Nout) {
            float bv = bias[col];
            bool is_sng = SNG && (col == 31 || col == 104 || col == 928);
            #pragma unroll
            for (int mi = 0; mi < 4; ++mi) {
                #pragma unroll
                for (int r = 0; r < 4; ++r) {
                    int row = m0 + wm + mi * 16 + quad * 4 + r;
                    float v = acc[mi][ni][r] + bv;
                    if (ACT == 1) v = (v > 0.f) ? v : (fast_exp(v) - 1.f);
                    else if (ACT == 2) v = fast_rcp(1.f + fast_exp(-v));
                    store_val(C, (size_t)row * ldc + col, v);
                    if constexpr (SNG) {
                        if (is_sng) sngl[(size_t)row * 929 + col] = v;
                    }
                }
            }
        }
    }
}

// ---------------------------------------------------------------------------
// Gumbel-softmax epilogue v2: no LDS, register-resident y, 2 rows per wave.
//   y2 = (logit + g)/TEMP * log2(e)
//      = 1.8033688*logit - 1.25*log2(-ln2*log2(u+eps) + eps)    [ln2*log2e=1]
//   p  = 2^(y2 - max) / sum(2^(y2 - max))
// Segments <=32 wide: lanes 0-31 process row A, lanes 32-63 row B in ONE pass;
// reductions use xor offsets < 32 so halves never mix. Wide segments (59, 76,
// 711) run full-wave per row. Compile-time offsets fold into load immediates.
// Singleton columns (31,104,928) already hold fp32 logits in out — untouched.
// ---------------------------------------------------------------------------
#define NEG_BIG (-1e30f)
#define Y2_LG   1.8033688011f   // 1.25 * log2(e)

__device__ __forceinline__ float y2_col(const uint16_t* __restrict__ rlg,
                                        const float* __restrict__ ru, int c) {
    float l2u   = __builtin_amdgcn_logf(ru[c] + GEPS);   // log2(u+eps)
    float inner = fmaf(-LN2, l2u, GEPS);                 // -ln(u+eps)+eps
    float l2i   = __builtin_amdgcn_logf(inner);          // log2(inner)
    return fmaf(Y2_LG, bf2f(rlg[c]), -1.25f * l2i);
}

template<int N, int OFF>
__device__ __forceinline__ void seg_small(const uint16_t* __restrict__ rlg,
                                          const float* __restrict__ ru,
                                          float* __restrict__ rout, int l32) {
    static_assert(N <= 32, "seg_small needs N<=32");
    constexpr int GS = (N <= 2) ? 2 : (N <= 4) ? 4 : (N <= 8) ? 8 : (N <= 16) ? 16 : 32;
    const bool act = l32 < N;
    const int  c   = OFF + l32;
    float y = act ? y2_col(rlg, ru, c) : NEG_BIG;
    float m = y;
    #pragma unroll
    for (int o = 1; o < GS; o <<= 1) m = fmaxf(m, __shfl_xor(m, o, 64));
    float e = act ? fast_exp2(y - m) : 0.f;
    float s = e;
    #pragma unroll
    for (int o = 1; o < GS; o <<= 1) s += __shfl_xor(s, o, 64);
    if (act) rout[c] = e * fast_rcp(s);
}

template<int N, int OFF>
__device__ __forceinline__ void seg_wide(const uint16_t* __restrict__ rlg,
                                         const float* __restrict__ ru,
                                         float* __restrict__ rout, int lane) {
    constexpr int IT = (N + 63) / 64;
    float y[IT];
    float m = NEG_BIG;
    #pragma unroll
    for (int i = 0; i < IT; ++i) {
        const int j = i * 64 + lane;
        y[i] = (j < N) ? y2_col(rlg, ru, OFF + j) : NEG_BIG;
        m = fmaxf(m, y[i]);
    }
    #pragma unroll
    for (int o = 1; o < 64; o <<= 1) m = fmaxf(m, __shfl_xor(m, o, 64));
    float s = 0.f;
    #pragma unroll
    for (int i = 0; i < IT; ++i) {
        float e = fast_exp2(y[i] - m);   // inactive lanes: 2^(-1e30) = 0
        y[i] = e;
        s += e;
    }
    #pragma unroll
    for (int o = 1; o < 64; o <<= 1) s += __shfl_xor(s, o, 64);
    const float inv = fast_rcp(s);
    #pragma unroll
    for (int i = 0; i < IT; ++i) {
        const int j = i * 64 + lane;
        if (j < N) rout[OFF + j] = y[i] * inv;
    }
}

__global__ __launch_bounds__(256)
void gumbel_epilogue(const uint16_t* __restrict__ lg, float* __restrict__ out,
                     const float* __restrict__ u, int B) {
    const int wave = threadIdx.x >> 6, lane = threadIdx.x & 63;
    const int l32  = lane & 31, half = lane >> 5;
    const int rowA = blockIdx.x * 8 + wave * 2;
    if (rowA >= B) return;

    const size_t baseA = (size_t)rowA * 929;
    const size_t baseB = baseA + 929;
    const size_t baseH = half ? baseB : baseA;

    // paired small segments: each 32-lane half handles its own row
    const uint16_t* lgH = lg  + baseH;
    const float*    uH  = u   + baseH;
    float*          oH  = out + baseH;
    seg_small<29,   0>(lgH, uH, oH, l32);
    seg_small< 2,  29>(lgH, uH, oH, l32);
    seg_small< 6,  32>(lgH, uH, oH, l32);
    seg_small< 7,  38>(lgH, uH, oH, l32);
    seg_small<24, 105>(lgH, uH, oH, l32);
    seg_small< 3, 916>(lgH, uH, oH, l32);
    seg_small< 9, 919>(lgH, uH, oH, l32);

    // wide segments: full wave, one row at a time (independent -> ILP)
    const uint16_t* lgA = lg + baseA; const float* uA = u + baseA; float* oA = out + baseA;
    const uint16_t* lgB = lg + baseB; const float* uB = u + baseB; float* oB = out + baseB;
    seg_wide< 59,  45>(lgA, uA, oA, lane);
    seg_wide< 59,  45>(lgB, uB, oB, lane);
    seg_wide< 76, 129>(lgA, uA, oA, lane);
    seg_wide< 76, 129>(lgB, uB, oB, lane);
    seg_wide<711, 205>(lgA, uA, oA, lane);
    seg_wide<711, 205>(lgB, uB, oB, lane);
}

// ---------------------------------------------------------------------------
extern "C" void kernel_launch(void* const* d_in, const int* in_sizes, int n_in,
                              void* d_out, int out_size, void* d_ws, size_t ws_size,
                              hipStream_t stream) {
    const float* x  = (const float*)d_in[0];
    const float* W1 = (const float*)d_in[1];
    const float* b1 = (const float*)d_in[2];
    const float* W2 = (const float*)d_in[3];
    const float* b2 = (const float*)d_in[4];
    const float* W3 = (const float*)d_in[5];
    const float* b3 = (const float*)d_in[6];
    const float* u  = (const float*)d_in[7];
    float* out = (float*)d_out;

    const int B = 32768, D = 128, H = 1024, O = 929, OP = 1024;

    char* ws = (char*)d_ws;
    uint16_t* xb  = (uint16_t*)ws; ws += (size_t)B * D * 2;   // 8 MB
    uint16_t* w1t = (uint16_t*)ws; ws += (size_t)H * D * 2;   // 0.25 MB
    uint16_t* w2t = (uint16_t*)ws; ws += (size_t)H * H * 2;   // 2 MB
    uint16_t* w3t = (uint16_t*)ws; ws += (size_t)OP * H * 2;  // 2 MB
    uint16_t* h1  = (uint16_t*)ws; ws += (size_t)B * H * 2;   // 64 MB
    uint16_t* h2  = (uint16_t*)ws; ws += (size_t)B * H * 2;   // 64 MB
    // logits (bf16, B x 929 = 61 MB) alias the h1 buffer — h1 is dead after GEMM2
    uint16_t* lg  = h1;

    cast_bf16<<<(B * D / 4 + 255) / 256, 256, 0, stream>>>(x, xb, B * D);
    transpose_cast<<<dim3(H / 64, D / 64), 256, 0, stream>>>(W1, w1t, D, H, H);
    transpose_cast<<<dim3(H / 64, H / 64), 256, 0, stream>>>(W2, w2t, H, H, H);
    transpose_cast<<<dim3(OP / 64, H / 64), 256, 0, stream>>>(W3, w3t, H, O, OP);

    // h1 = elu(x @ W1 + b1)
    gemm_bt<1, uint16_t, false><<<dim3(H / 128, B / 128), 256, 0, stream>>>(
        xb, w1t, b1, h1, nullptr, D, H, H);
    // h2 = sigmoid(h1 @ W2 + b2)
    gemm_bt<2, uint16_t, false><<<dim3(H / 128, B / 128), 256, 0, stream>>>(
        h1, w2t, b2, h2, nullptr, H, H, H);
    // logits -> bf16 ws buffer; fp32 singleton cols (31,104,928) -> d_out
    gemm_bt<0, uint16_t, true><<<dim3(OP / 128, B / 128), 256, 0, stream>>>(
        h2, w3t, b3, lg, out, H, O, O);

    // gumbel softmax: bf16 logits -> fp32 out (singletons already final)
    gumbel_epilogue<<<B / 8, 256, 0, stream>>>(lg, out, u, B);
}

// Round 5
// 486.552 us; speedup vs baseline: 1.1137x; 1.0421x over previous
//
#include <hip/hip_runtime.h>
#include <hip/hip_bf16.h>
#include <stdint.h>

#define GEPS 1e-20f

typedef __bf16 bf16x8 __attribute__((ext_vector_type(8)));
typedef float  f32x4  __attribute__((ext_vector_type(4)));

typedef const __attribute__((address_space(1))) uint32_t* gptr32;
typedef __attribute__((address_space(3))) uint32_t* lptr32;

__device__ __forceinline__ void load_lds16(const void* g, void* l) {
    __builtin_amdgcn_global_load_lds((gptr32)g, (lptr32)l, 16, 0, 0);
}

__device__ __forceinline__ uint16_t f2bf(float v) {
    __hip_bfloat16 b = __float2bfloat16(v);
    return *(uint16_t*)&b;
}
__device__ __forceinline__ float bf2f(uint16_t b) {
    uint32_t u = (uint32_t)b << 16;
    return __builtin_bit_cast(float, u);
}

// hardware transcendentals: v_log_f32 = log2(x), v_exp_f32 = 2^x  (~1 ULP)
#define LN2   0.69314718056f
#define LOG2E 1.44269504089f
__device__ __forceinline__ float fast_log(float x) { return __builtin_amdgcn_logf(x) * LN2; }
__device__ __forceinline__ float fast_exp(float x) { return __builtin_amdgcn_exp2f(x * LOG2E); }
__device__ __forceinline__ float fast_exp2(float x) { return __builtin_amdgcn_exp2f(x); }
__device__ __forceinline__ float fast_rcp(float x)  { return __builtin_amdgcn_rcpf(x); }

__device__ __forceinline__ void store_val(uint16_t* C, size_t idx, float v) { C[idx] = f2bf(v); }
__device__ __forceinline__ void store_val(float* C, size_t idx, float v)    { C[idx] = v; }

// ---------------------------------------------------------------------------
// cast fp32 -> bf16, vectorized (n must be multiple of 4)
// ---------------------------------------------------------------------------
__global__ void cast_bf16(const float* __restrict__ in, uint16_t* __restrict__ out, int n) {
    int i = (blockIdx.x * blockDim.x + threadIdx.x) * 4;
    if (i < n) {
        float4 v = *(const float4*)(in + i);
        ushort4 o;
        o.x = f2bf(v.x); o.y = f2bf(v.y); o.z = f2bf(v.z); o.w = f2bf(v.w);
        *(ushort4*)(out + i) = o;
    }
}

// ---------------------------------------------------------------------------
// W (K x N, fp32, row-major) -> Wt (Npad x K, bf16, row-major), zero-pad n>=N
// ---------------------------------------------------------------------------
__global__ void transpose_cast(const float* __restrict__ W, uint16_t* __restrict__ Wt,
                               int K, int N, int Npad) {
    __shared__ float tile[64][65];
    const int k0 = blockIdx.y * 64, n0 = blockIdx.x * 64;
    const int tx = threadIdx.x & 63, ty = threadIdx.x >> 6;
    for (int r = ty; r < 64; r += 4) {
        int n = n0 + tx;
        tile[r][tx] = (n < N) ? W[(size_t)(k0 + r) * N + n] : 0.f;
    }
    __syncthreads();
    for (int r = ty; r < 64; r += 4) {
        Wt[(size_t)(n0 + r) * K + k0 + tx] = f2bf(tile[tx][r]);
    }
}

// ---------------------------------------------------------------------------
// KNOWN-GOOD 128x128 GEMM (verified rounds 0-1): C = act(A @ Bt^T + bias)
// Used for GEMM1 (K=128) where the deep pipeline doesn't pay anyway.
// ---------------------------------------------------------------------------
template<int ACT, typename OutT, bool SNG>
__global__ __launch_bounds__(256)
void gemm_bt(const uint16_t* __restrict__ A, const uint16_t* __restrict__ Bt,
             const float* __restrict__ bias, OutT* __restrict__ C,
             float* __restrict__ sngl,
             int K, int Nout, int ldc) {
    __shared__ __align__(16) uint16_t As[128 * 32];
    __shared__ __align__(16) uint16_t Bs[128 * 32];

    const int t    = threadIdx.x;
    const int wave = t >> 6, lane = t & 63;

    const int nbx = gridDim.x;
    const int bid = blockIdx.y * nbx + blockIdx.x;
    const int xcd = bid & 7;
    const int s   = bid >> 3;
    const int nidx = s % nbx;
    const int midx = xcd * (gridDim.y >> 3) + s / nbx;

    const int m0 = midx * 128, n0 = nidx * 128;
    const int wm = (wave >> 1) * 64, wn = (wave & 1) * 64;
    const int quad = lane >> 4;
    const int qk   = quad * 8;
    const int r15  = lane & 15;

    f32x4 acc[4][4] = {};

    const uint16_t* Ag = A  + (size_t)m0 * K;
    const uint16_t* Bg = Bt + (size_t)n0 * K;

    for (int k0 = 0; k0 < K; k0 += 32) {
        __syncthreads();
        #pragma unroll
        for (int rd = 0; rd < 2; ++rd) {
            int c = t + rd * 256;            // 16B-chunk index, 0..511
            int row = c >> 2, kc = (c & 3) * 8;
            load_lds16(Ag + (size_t)row * K + k0 + kc, &As[c * 8]);
            load_lds16(Bg + (size_t)row * K + k0 + kc, &Bs[c * 8]);
        }
        __syncthreads();

        bf16x8 a[4], b[4];
        #pragma unroll
        for (int i = 0; i < 4; ++i)
            a[i] = *(const bf16x8*)&As[(wm + i * 16 + r15) * 32 + qk];
        #pragma unroll
        for (int i = 0; i < 4; ++i)
            b[i] = *(const bf16x8*)&Bs[(wn + i * 16 + r15) * 32 + qk];

        #pragma unroll
        for (int mi = 0; mi < 4; ++mi)
            #pragma unroll
            for (int ni = 0; ni < 4; ++ni)
                acc[mi][ni] = __builtin_amdgcn_mfma_f32_16x16x32_bf16(
                    a[mi], b[ni], acc[mi][ni], 0, 0, 0);
    }

    #pragma unroll
    for (int ni = 0; ni < 4; ++ni) {
        int col = n0 + wn + ni * 16 + r15;
        if (col < Nout) {
            float bv = bias[col];
            bool is_sng = SNG && (col == 31 || col == 104 || col == 928);
            #pragma unroll
            for (int mi = 0; mi < 4; ++mi) {
                #pragma unroll
                for (int r = 0; r < 4; ++r) {
                    int row = m0 + wm + mi * 16 + quad * 4 + r;
                    float v = acc[mi][ni][r] + bv;
                    if (ACT == 1) v = (v > 0.f) ? v : (fast_exp(v) - 1.f);
                    else if (ACT == 2) v = fast_rcp(1.f + fast_exp(-v));
                    store_val(C, (size_t)row * ldc + col, v);
                    if constexpr (SNG) {
                        if (is_sng) sngl[(size_t)row * 929 + col] = v;
                    }
                }
            }
        }
    }
}

// ---------------------------------------------------------------------------
// 256x256 8-phase GEMM (counted vmcnt):  C = act(A @ Bt^T + bias)
// A: M x K bf16 row-major.  Bt: Npad x K bf16 row-major (Npad mult of 256).
// 512 threads = 8 waves (2M x 4N); per-wave output 128x64; BK=64; LDS 128 KiB
// (2 K-tile double buffer).  16x16x32 bf16 MFMA, 64 MFMA/K-tile/wave.
//
// LDS layout per matrix tile: [256 rows][64 cols] bf16, row stride 128 B,
// XOR-swizzled: byte ^= (row&7)<<4. global_load_lds writes LINEARLY; the
// source global address is inverse-swizzled (both-sides rule, G21).
//
// 8-phase schedule per iteration (2 K-tiles: even->buf0, odd->buf1).
// Quadrant order per K-tile: (m0,n0)(m0,n1)(m1,n1)(m1,n0); B frags for the
// whole K-tile stay in registers, so buf.B is dead after phase 2 and buf.A
// after phase 3 (post-MFMA barrier = all waves' ds_reads completed).
// Stage schedule (tile tN = 2ki+N), each phase stages 1 half-tile (2 loads):
//   P1: buf1.A0<-t1   P2: buf1.A1<-t1   P3: buf0.B0<-t2  P4: buf0.B1<-t2
//   P5: buf0.A0<-t2   P6: buf0.A1<-t2   P7: buf1.B0<-t3  P8: buf1.B1<-t3
// vmcnt(4) ONLY at end of P4/P8 (FIFO retirement): completes everything
// except the newest 2 half-stages; ledger verified by hand (see notes).
// Rounds 3/4 proved this schedule race-free (bit-identical output across
// counted vs drain-to-zero variants); the failure was a call-site Nout bug.
// ---------------------------------------------------------------------------
#define BARRIER() asm volatile("s_barrier" ::: "memory")
#define LGKM0()   do { asm volatile("s_waitcnt lgkmcnt(0)" ::: "memory"); \
                       __builtin_amdgcn_sched_barrier(0); } while (0)
#define VMW4()    asm volatile("s_waitcnt vmcnt(4)" ::: "memory")
#define VMW0()    asm volatile("s_waitcnt vmcnt(0)" ::: "memory")
#define PRIO1()   __builtin_amdgcn_s_setprio(1)
#define PRIO0()   __builtin_amdgcn_s_setprio(0)

template<int ACT, typename OutT, bool SNG, int K>
__global__ __launch_bounds__(512, 2)
void gemm256(const uint16_t* __restrict__ A, const uint16_t* __restrict__ Bt,
             const float* __restrict__ bias, OutT* __restrict__ C,
             float* __restrict__ sngl, int Nout, int ldc) {
    constexpr int NT = K / 64;           // K-tiles
    constexpr int NI = NT / 2;           // iterations (2 K-tiles each)
    constexpr int KB = K * 2;            // global row stride, bytes
    __shared__ __align__(16) char lds[131072];
    constexpr int AOFF0 = 0, BOFF0 = 32768, AOFF1 = 65536, BOFF1 = 98304;

    const int t = threadIdx.x;
    const int wave = t >> 6, lane = t & 63;
    const int quad = lane >> 4, r15 = lane & 15;
    const int wm = (wave >> 2) * 128, wn = (wave & 3) * 64;

    // ---- XCD-aware block remap (gridDim.y divisible by 8) ----
    const int nbx = gridDim.x;
    const int bid = blockIdx.y * nbx + blockIdx.x;
    const int xcd = bid & 7;
    const int sb  = bid >> 3;
    const int nidx = sb % nbx;
    const int midx = xcd * (gridDim.y >> 3) + sb / nbx;
    const int m0 = midx * 256, n0 = nidx * 256;

    // ---- staging addresses ----
    const int srow = t >> 3;                          // 0..63
    const int scb  = ((t & 7) ^ (srow & 7)) << 4;     // inverse-swizzled src col byte
    const char* Asrc = (const char*)A  + (size_t)(m0 + srow) * KB + scb;
    const char* Bsrc = (const char*)Bt + (size_t)(n0 + srow) * KB + scb;

    // ---- LDS read addressing (swizzled) ----
    const int sx   = (r15 & 7) << 4;
    const int cb0  = (quad * 16) ^ sx;        // kk = 0: chunk quad
    const int cb1  = (64 + quad * 16) ^ sx;   // kk = 1: chunk 4+quad
    const int aRow = (wm + r15) * 128;
    const int bRow = (wn + r15) * 128;

    f32x4 acc[8][4] = {};
    bf16x8 a[4][2], b[4][2];

#define STG(src, half, tile, ldsOff)                                                      \
    do {                                                                                  \
        const char* _s = (src) + (size_t)((half) * 128) * KB + (size_t)(tile) * 128;      \
        load_lds16(_s,                   &lds[(ldsOff) + (half) * 16384 + t * 16]);       \
        load_lds16(_s + (size_t)64 * KB, &lds[(ldsOff) + (half) * 16384 + 8192 + t * 16]);\
    } while (0)

    auto ldA = [&](int buf, int mh) {
        #pragma unroll
        for (int mi = 0; mi < 4; ++mi) {
            const int base = buf * 65536 + aRow + (mh * 4 + mi) * 2048;
            a[mi][0] = *(const bf16x8*)&lds[base + cb0];
            a[mi][1] = *(const bf16x8*)&lds[base + cb1];
        }
    };
    auto ldB = [&](int buf, int nh) {
        #pragma unroll
        for (int ni = 0; ni < 2; ++ni) {
            const int base = buf * 65536 + 32768 + bRow + (nh * 2 + ni) * 2048;
            b[nh * 2 + ni][0] = *(const bf16x8*)&lds[base + cb0];
            b[nh * 2 + ni][1] = *(const bf16x8*)&lds[base + cb1];
        }
    };
    auto mfmaQ = [&](int mlo, int nlo) {
        #pragma unroll
        for (int mi = 0; mi < 4; ++mi)
            #pragma unroll
            for (int ni = 0; ni < 2; ++ni)
                #pragma unroll
                for (int kk = 0; kk < 2; ++kk)
                    acc[mlo + mi][nlo + ni] = __builtin_amdgcn_mfma_f32_16x16x32_bf16(
                        a[mi][kk], b[nlo + ni][kk], acc[mlo + mi][nlo + ni], 0, 0, 0);
    };

    // ---- prologue: tile0 -> buf0, tile1.B -> buf1; vmcnt(4) keeps buf1.B in flight
    STG(Bsrc, 0, 0, BOFF0); STG(Bsrc, 1, 0, BOFF0);
    STG(Asrc, 0, 0, AOFF0); STG(Asrc, 1, 0, AOFF0);
    STG(Bsrc, 0, 1, BOFF1); STG(Bsrc, 1, 1, BOFF1);
    VMW4(); BARRIER();

    #pragma unroll 1
    for (int ki = 0; ki < NI; ++ki) {
        const int t1 = 2 * ki + 1;
        const int p0 = (2 * ki + 2) & (NT - 1);   // wrap on final iter: restages
        const int p1 = (2 * ki + 3) & (NT - 1);   // same data into dead buffers

        // P1: buf0 (m0-3, n0-1)
        ldA(0, 0); ldB(0, 0);
        STG(Asrc, 0, t1, AOFF1);
        BARRIER(); LGKM0();
        PRIO1(); mfmaQ(0, 0); PRIO0();
        BARRIER();

        // P2: buf0 (m0-3, n2-3)
        ldB(0, 1);
        STG(Asrc, 1, t1, AOFF1);
        BARRIER(); LGKM0();
        PRIO1(); mfmaQ(0, 2); PRIO0();
        BARRIER();

        // P3: buf0 (m4-7, n2-3)   [buf0.B dead after P2 -> safe to restage]
        ldA(0, 1);
        STG(Bsrc, 0, p0, BOFF0);
        BARRIER(); LGKM0();
        PRIO1(); mfmaQ(4, 2); PRIO0();
        BARRIER();

        // P4: buf0 (m4-7, n0-1); vmcnt gate for buf1 reads in P5
        STG(Bsrc, 1, p0, BOFF0);
        BARRIER();
        PRIO1(); mfmaQ(4, 0); PRIO0();
        VMW4(); BARRIER();

        // P5: buf1 (m0-3, n0-1)   [buf0.A dead after P3 -> safe to restage]
        ldA(1, 0); ldB(1, 0);
        STG(Asrc, 0, p0, AOFF0);
        BARRIER(); LGKM0();
        PRIO1(); mfmaQ(0, 0); PRIO0();
        BARRIER();

        // P6: buf1 (m0-3, n2-3)
        ldB(1, 1);
        STG(Asrc, 1, p0, AOFF0);
        BARRIER(); LGKM0();
        PRIO1(); mfmaQ(0, 2); PRIO0();
        BARRIER();

        // P7: buf1 (m4-7, n2-3)   [buf1.B dead after P6]
        ldA(1, 1);
        STG(Bsrc, 0, p1, BOFF1);
        BARRIER(); LGKM0();
        PRIO1(); mfmaQ(4, 2); PRIO0();
        BARRIER();

        // P8: buf1 (m4-7, n0-1); vmcnt gate for buf0 reads in next P1
        STG(Bsrc, 1, p1, BOFF1);
        BARRIER();
        PRIO1(); mfmaQ(4, 0); PRIO0();
        VMW4(); BARRIER();
    }
    VMW0();   // drain trailing (wrapped) stages before epilogue

#undef STG

    // ---- epilogue: C/D layout col = lane&15, row = quad*4 + reg  [m89] ----
    #pragma unroll
    for (int ni = 0; ni < 4; ++ni) {
        const int col = n0 + wn + ni * 16 + r15;
        if (col < Nout) {
            const float bv = bias[col];
            const bool is_sng = SNG && (col == 31 || col == 104 || col == 928);
            #pragma unroll
            for (int mi = 0; mi < 8; ++mi) {
                #pragma unroll
                for (int r = 0; r < 4; ++r) {
                    const int row = m0 + wm + mi * 16 + quad * 4 + r;
                    float v = acc[mi][ni][r] + bv;
                    if (ACT == 1) v = (v > 0.f) ? v : (fast_exp(v) - 1.f);
                    else if (ACT == 2) v = fast_rcp(1.f + fast_exp(-v));
                    store_val(C, (size_t)row * ldc + col, v);
                    if constexpr (SNG) {
                        if (is_sng) sngl[(size_t)row * 929 + col] = v;
                    }
                }
            }
        }
    }
}

// ---------------------------------------------------------------------------
// Gumbel-softmax epilogue v2: no LDS, register-resident y, 2 rows per wave.
//   y2 = (logit + g)/TEMP * log2(e)
//      = 1.8033688*logit - 1.25*log2(-ln2*log2(u+eps) + eps)    [ln2*log2e=1]
//   p  = 2^(y2 - max) / sum(2^(y2 - max))
// ---------------------------------------------------------------------------
#define NEG_BIG (-1e30f)
#define Y2_LG   1.8033688011f   // 1.25 * log2(e)

__device__ __forceinline__ float y2_col(const uint16_t* __restrict__ rlg,
                                        const float* __restrict__ ru, int c) {
    float l2u   = __builtin_amdgcn_logf(ru[c] + GEPS);   // log2(u+eps)
    float inner = fmaf(-LN2, l2u, GEPS);                 // -ln(u+eps)+eps
    float l2i   = __builtin_amdgcn_logf(inner);          // log2(inner)
    return fmaf(Y2_LG, bf2f(rlg[c]), -1.25f * l2i);
}

template<int N, int OFF>
__device__ __forceinline__ void seg_small(const uint16_t* __restrict__ rlg,
                                          const float* __restrict__ ru,
                                          float* __restrict__ rout, int l32) {
    static_assert(N <= 32, "seg_small needs N<=32");
    constexpr int GS = (N <= 2) ? 2 : (N <= 4) ? 4 : (N <= 8) ? 8 : (N <= 16) ? 16 : 32;
    const bool act = l32 < N;
    const int  c   = OFF + l32;
    float y = act ? y2_col(rlg, ru, c) : NEG_BIG;
    float m = y;
    #pragma unroll
    for (int o = 1; o < GS; o <<= 1) m = fmaxf(m, __shfl_xor(m, o, 64));
    float e = act ? fast_exp2(y - m) : 0.f;
    float s = e;
    #pragma unroll
    for (int o = 1; o < GS; o <<= 1) s += __shfl_xor(s, o, 64);
    if (act) rout[c] = e * fast_rcp(s);
}

template<int N, int OFF>
__device__ __forceinline__ void seg_wide(const uint16_t* __restrict__ rlg,
                                         const float* __restrict__ ru,
                                         float* __restrict__ rout, int lane) {
    constexpr int IT = (N + 63) / 64;
    float y[IT];
    float m = NEG_BIG;
    #pragma unroll
    for (int i = 0; i < IT; ++i) {
        const int j = i * 64 + lane;
        y[i] = (j < N) ? y2_col(rlg, ru, OFF + j) : NEG_BIG;
        m = fmaxf(m, y[i]);
    }
    #pragma unroll
    for (int o = 1; o < 64; o <<= 1) m = fmaxf(m, __shfl_xor(m, o, 64));
    float s = 0.f;
    #pragma unroll
    for (int i = 0; i < IT; ++i) {
        float e = fast_exp2(y[i] - m);   // inactive lanes: 2^(-1e30) = 0
        y[i] = e;
        s += e;
    }
    #pragma unroll
    for (int o = 1; o < 64; o <<= 1) s += __shfl_xor(s, o, 64);
    const float inv = fast_rcp(s);
    #pragma unroll
    for (int i = 0; i < IT; ++i) {
        const int j = i * 64 + lane;
        if (j < N) rout[OFF + j] = y[i] * inv;
    }
}

__global__ __launch_bounds__(256)
void gumbel_epilogue(const uint16_t* __restrict__ lg, float* __restrict__ out,
                     const float* __restrict__ u, int B) {
    const int wave = threadIdx.x >> 6, lane = threadIdx.x & 63;
    const int l32  = lane & 31, half = lane >> 5;
    const int rowA = blockIdx.x * 8 + wave * 2;
    if (rowA >= B) return;

    const size_t baseA = (size_t)rowA * 929;
    const size_t baseB = baseA + 929;
    const size_t baseH = half ? baseB : baseA;

    // paired small segments: each 32-lane half handles its own row
    const uint16_t* lgH = lg  + baseH;
    const float*    uH  = u   + baseH;
    float*          oH  = out + baseH;
    seg_small<29,   0>(lgH, uH, oH, l32);
    seg_small< 2,  29>(lgH, uH, oH, l32);
    seg_small< 6,  32>(lgH, uH, oH, l32);
    seg_small< 7,  38>(lgH, uH, oH, l32);
    seg_small<24, 105>(lgH, uH, oH, l32);
    seg_small< 3, 916>(lgH, uH, oH, l32);
    seg_small< 9, 919>(lgH, uH, oH, l32);

    // wide segments: full wave, one row at a time (independent -> ILP)
    const uint16_t* lgA = lg + baseA; const float* uA = u + baseA; float* oA = out + baseA;
    const uint16_t* lgB = lg + baseB; const float* uB = u + baseB; float* oB = out + baseB;
    seg_wide< 59,  45>(lgA, uA, oA, lane);
    seg_wide< 59,  45>(lgB, uB, oB, lane);
    seg_wide< 76, 129>(lgA, uA, oA, lane);
    seg_wide< 76, 129>(lgB, uB, oB, lane);
    seg_wide<711, 205>(lgA, uA, oA, lane);
    seg_wide<711, 205>(lgB, uB, oB, lane);
}

// ---------------------------------------------------------------------------
extern "C" void kernel_launch(void* const* d_in, const int* in_sizes, int n_in,
                              void* d_out, int out_size, void* d_ws, size_t ws_size,
                              hipStream_t stream) {
    const float* x  = (const float*)d_in[0];
    const float* W1 = (const float*)d_in[1];
    const float* b1 = (const float*)d_in[2];
    const float* W2 = (const float*)d_in[3];
    const float* b2 = (const float*)d_in[4];
    const float* W3 = (const float*)d_in[5];
    const float* b3 = (const float*)d_in[6];
    const float* u  = (const float*)d_in[7];
    float* out = (float*)d_out;

    const int B = 32768, D = 128, H = 1024, O = 929, OP = 1024;

    char* ws = (char*)d_ws;
    uint16_t* xb  = (uint16_t*)ws; ws += (size_t)B * D * 2;   // 8 MB
    uint16_t* w1t = (uint16_t*)ws; ws += (size_t)H * D * 2;   // 0.25 MB
    uint16_t* w2t = (uint16_t*)ws; ws += (size_t)H * H * 2;   // 2 MB
    uint16_t* w3t = (uint16_t*)ws; ws += (size_t)OP * H * 2;  // 2 MB
    uint16_t* h1  = (uint16_t*)ws; ws += (size_t)B * H * 2;   // 64 MB
    uint16_t* h2  = (uint16_t*)ws; ws += (size_t)B * H * 2;   // 64 MB
    // logits (bf16, B x 929 = 61 MB) alias the h1 buffer — h1 is dead after GEMM2
    uint16_t* lg  = h1;

    cast_bf16<<<(B * D / 4 + 255) / 256, 256, 0, stream>>>(x, xb, B * D);
    transpose_cast<<<dim3(H / 64, D / 64), 256, 0, stream>>>(W1, w1t, D, H, H);
    transpose_cast<<<dim3(H / 64, H / 64), 256, 0, stream>>>(W2, w2t, H, H, H);
    transpose_cast<<<dim3(OP / 64, H / 64), 256, 0, stream>>>(W3, w3t, H, O, OP);

    // h1 = elu(x @ W1 + b1)   (K=128: known-good 128x128 kernel)
    gemm_bt<1, uint16_t, false><<<dim3(H / 128, B / 128), 256, 0, stream>>>(
        xb, w1t, b1, h1, nullptr, D, H, H);
    // h2 = sigmoid(h1 @ W2 + b2)   (Nout = ldc = H)
    gemm256<2, uint16_t, false, 1024><<<dim3(H / 256, B / 256), 512, 0, stream>>>(
        h1, w2t, b2, h2, nullptr, H, H);
    // logits -> bf16 ws buffer; fp32 singleton cols (31,104,928) -> d_out
    // Nout = ldc = O (929)!  [round-3/4 bug: Nout=H wrote cols 929..1023,
    // aliasing the next row's logits at lg[row*929 + col]]
    gemm256<0, uint16_t, true, 1024><<<dim3(OP / 256, B / 256), 512, 0, stream>>>(
        h2, w3t, b3, lg, out, O, O);

    // gumbel softmax: bf16 logits -> fp32 out (singletons already final)
    gumbel_epilogue<<<B / 8, 256, 0, stream>>>(lg, out, u, B);
}

// Round 6
// 484.768 us; speedup vs baseline: 1.1178x; 1.0037x over previous
//
#include <hip/hip_runtime.h>
#include <hip/hip_bf16.h>
#include <stdint.h>

#define GEPS 1e-20f

typedef __bf16 bf16x8 __attribute__((ext_vector_type(8)));
typedef float  f32x4  __attribute__((ext_vector_type(4)));

typedef const __attribute__((address_space(1))) uint32_t* gptr32;
typedef __attribute__((address_space(3))) uint32_t* lptr32;

__device__ __forceinline__ void load_lds16(const void* g, void* l) {
    __builtin_amdgcn_global_load_lds((gptr32)g, (lptr32)l, 16, 0, 0);
}

__device__ __forceinline__ uint16_t f2bf(float v) {
    __hip_bfloat16 b = __float2bfloat16(v);
    return *(uint16_t*)&b;
}
__device__ __forceinline__ float bf2f(uint16_t b) {
    uint32_t u = (uint32_t)b << 16;
    return __builtin_bit_cast(float, u);
}

// hardware transcendentals: v_log_f32 = log2(x), v_exp_f32 = 2^x  (~1 ULP)
#define LN2   0.69314718056f
#define LOG2E 1.44269504089f
__device__ __forceinline__ float fast_log(float x) { return __builtin_amdgcn_logf(x) * LN2; }
__device__ __forceinline__ float fast_exp(float x) { return __builtin_amdgcn_exp2f(x * LOG2E); }
__device__ __forceinline__ float fast_exp2(float x) { return __builtin_amdgcn_exp2f(x); }
__device__ __forceinline__ float fast_rcp(float x)  { return __builtin_amdgcn_rcpf(x); }

__device__ __forceinline__ void store_val(uint16_t* C, size_t idx, float v) { C[idx] = f2bf(v); }
__device__ __forceinline__ void store_val(float* C, size_t idx, float v)    { C[idx] = v; }

// ---------------------------------------------------------------------------
// cast fp32 -> bf16, vectorized (n must be multiple of 4)
// ---------------------------------------------------------------------------
__global__ void cast_bf16(const float* __restrict__ in, uint16_t* __restrict__ out, int n) {
    int i = (blockIdx.x * blockDim.x + threadIdx.x) * 4;
    if (i < n) {
        float4 v = *(const float4*)(in + i);
        ushort4 o;
        o.x = f2bf(v.x); o.y = f2bf(v.y); o.z = f2bf(v.z); o.w = f2bf(v.w);
        *(ushort4*)(out + i) = o;
    }
}

// ---------------------------------------------------------------------------
// W (K x N, fp32, row-major) -> Wt (Npad x K, bf16, row-major), zero-pad n>=N
// ---------------------------------------------------------------------------
__global__ void transpose_cast(const float* __restrict__ W, uint16_t* __restrict__ Wt,
                               int K, int N, int Npad) {
    __shared__ float tile[64][65];
    const int k0 = blockIdx.y * 64, n0 = blockIdx.x * 64;
    const int tx = threadIdx.x & 63, ty = threadIdx.x >> 6;
    for (int r = ty; r < 64; r += 4) {
        int n = n0 + tx;
        tile[r][tx] = (n < N) ? W[(size_t)(k0 + r) * N + n] : 0.f;
    }
    __syncthreads();
    for (int r = ty; r < 64; r += 4) {
        Wt[(size_t)(n0 + r) * K + k0 + tx] = f2bf(tile[tx][r]);
    }
}

// ---------------------------------------------------------------------------
// KNOWN-GOOD 128x128 GEMM (verified rounds 0-1): C = act(A @ Bt^T + bias)
// Used for GEMM1 (K=128) where the deep pipeline doesn't pay anyway.
// ---------------------------------------------------------------------------
template<int ACT, typename OutT, bool SNG>
__global__ __launch_bounds__(256)
void gemm_bt(const uint16_t* __restrict__ A, const uint16_t* __restrict__ Bt,
             const float* __restrict__ bias, OutT* __restrict__ C,
             float* __restrict__ sngl,
             int K, int Nout, int ldc) {
    __shared__ __align__(16) uint16_t As[128 * 32];
    __shared__ __align__(16) uint16_t Bs[128 * 32];

    const int t    = threadIdx.x;
    const int wave = t >> 6, lane = t & 63;

    const int nbx = gridDim.x;
    const int bid = blockIdx.y * nbx + blockIdx.x;
    const int xcd = bid & 7;
    const int s   = bid >> 3;
    const int nidx = s % nbx;
    const int midx = xcd * (gridDim.y >> 3) + s / nbx;

    const int m0 = midx * 128, n0 = nidx * 128;
    const int wm = (wave >> 1) * 64, wn = (wave & 1) * 64;
    const int quad = lane >> 4;
    const int qk   = quad * 8;
    const int r15  = lane & 15;

    f32x4 acc[4][4] = {};

    const uint16_t* Ag = A  + (size_t)m0 * K;
    const uint16_t* Bg = Bt + (size_t)n0 * K;

    for (int k0 = 0; k0 < K; k0 += 32) {
        __syncthreads();
        #pragma unroll
        for (int rd = 0; rd < 2; ++rd) {
            int c = t + rd * 256;            // 16B-chunk index, 0..511
            int row = c >> 2, kc = (c & 3) * 8;
            load_lds16(Ag + (size_t)row * K + k0 + kc, &As[c * 8]);
            load_lds16(Bg + (size_t)row * K + k0 + kc, &Bs[c * 8]);
        }
        __syncthreads();

        bf16x8 a[4], b[4];
        #pragma unroll
        for (int i = 0; i < 4; ++i)
            a[i] = *(const bf16x8*)&As[(wm + i * 16 + r15) * 32 + qk];
        #pragma unroll
        for (int i = 0; i < 4; ++i)
            b[i] = *(const bf16x8*)&Bs[(wn + i * 16 + r15) * 32 + qk];

        #pragma unroll
        for (int mi = 0; mi < 4; ++mi)
            #pragma unroll
            for (int ni = 0; ni < 4; ++ni)
                acc[mi][ni] = __builtin_amdgcn_mfma_f32_16x16x32_bf16(
                    a[mi], b[ni], acc[mi][ni], 0, 0, 0);
    }

    #pragma unroll
    for (int ni = 0; ni < 4; ++ni) {
        int col = n0 + wn + ni * 16 + r15;
        if (col < Nout) {
            float bv = bias[col];
            bool is_sng = SNG && (col == 31 || col == 104 || col == 928);
            #pragma unroll
            for (int mi = 0; mi < 4; ++mi) {
                #pragma unroll
                for (int r = 0; r < 4; ++r) {
                    int row = m0 + wm + mi * 16 + quad * 4 + r;
                    float v = acc[mi][ni][r] + bv;
                    if (ACT == 1) v = (v > 0.f) ? v : (fast_exp(v) - 1.f);
                    else if (ACT == 2) v = fast_rcp(1.f + fast_exp(-v));
                    store_val(C, (size_t)row * ldc + col, v);
                    if constexpr (SNG) {
                        if (is_sng) sngl[(size_t)row * 929 + col] = v;
                    }
                }
            }
        }
    }
}

// ---------------------------------------------------------------------------
// 256x256 8-phase GEMM (counted vmcnt):  C = act(A @ Bt^T + bias)
// Structure as round 5 (verified correct), ONE change: no forced
// lgkmcnt(0)+sched_barrier before the MFMA cluster. The compiler tracks the
// C++ ds_reads and emits fine-grained lgkmcnt(N) per consumer, so MFMAs can
// start while later ds_reads drain. A plain lgkmcnt(0) sits just BEFORE the
// trailing barrier (asm-asm ordered) — that is all the cross-wave restage
// proof needs: my reads are complete before any wave passes the barrier and
// overwrites the region. [m141: forced drains+sched walls cost ~40%]
// ---------------------------------------------------------------------------
#define BARRIER() asm volatile("s_barrier" ::: "memory")
#define LGKM0()   asm volatile("s_waitcnt lgkmcnt(0)" ::: "memory")
#define VMW4()    asm volatile("s_waitcnt vmcnt(4)" ::: "memory")
#define VMW0()    asm volatile("s_waitcnt vmcnt(0)" ::: "memory")
#define PRIO1()   __builtin_amdgcn_s_setprio(1)
#define PRIO0()   __builtin_amdgcn_s_setprio(0)

template<int ACT, typename OutT, bool SNG, int K>
__global__ __launch_bounds__(512, 2)
void gemm256(const uint16_t* __restrict__ A, const uint16_t* __restrict__ Bt,
             const float* __restrict__ bias, OutT* __restrict__ C,
             float* __restrict__ sngl, int Nout, int ldc) {
    constexpr int NT = K / 64;           // K-tiles
    constexpr int NI = NT / 2;           // iterations (2 K-tiles each)
    constexpr int KB = K * 2;            // global row stride, bytes
    __shared__ __align__(16) char lds[131072];
    constexpr int AOFF0 = 0, BOFF0 = 32768, AOFF1 = 65536, BOFF1 = 98304;

    const int t = threadIdx.x;
    const int wave = t >> 6, lane = t & 63;
    const int quad = lane >> 4, r15 = lane & 15;
    const int wm = (wave >> 2) * 128, wn = (wave & 3) * 64;

    // ---- XCD-aware block remap (gridDim.y divisible by 8) ----
    const int nbx = gridDim.x;
    const int bid = blockIdx.y * nbx + blockIdx.x;
    const int xcd = bid & 7;
    const int sb  = bid >> 3;
    const int nidx = sb % nbx;
    const int midx = xcd * (gridDim.y >> 3) + sb / nbx;
    const int m0 = midx * 256, n0 = nidx * 256;

    // ---- staging addresses ----
    const int srow = t >> 3;                          // 0..63
    const int scb  = ((t & 7) ^ (srow & 7)) << 4;     // inverse-swizzled src col byte
    const char* Asrc = (const char*)A  + (size_t)(m0 + srow) * KB + scb;
    const char* Bsrc = (const char*)Bt + (size_t)(n0 + srow) * KB + scb;

    // ---- LDS read addressing (swizzled) ----
    const int sx   = (r15 & 7) << 4;
    const int cb0  = (quad * 16) ^ sx;        // kk = 0: chunk quad
    const int cb1  = (64 + quad * 16) ^ sx;   // kk = 1: chunk 4+quad
    const int aRow = (wm + r15) * 128;
    const int bRow = (wn + r15) * 128;

    f32x4 acc[8][4] = {};
    bf16x8 a[4][2], b[4][2];

#define STG(src, half, tile, ldsOff)                                                      \
    do {                                                                                  \
        const char* _s = (src) + (size_t)((half) * 128) * KB + (size_t)(tile) * 128;      \
        load_lds16(_s,                   &lds[(ldsOff) + (half) * 16384 + t * 16]);       \
        load_lds16(_s + (size_t)64 * KB, &lds[(ldsOff) + (half) * 16384 + 8192 + t * 16]);\
    } while (0)

    auto ldA = [&](int buf, int mh) {
        #pragma unroll
        for (int mi = 0; mi < 4; ++mi) {
            const int base = buf * 65536 + aRow + (mh * 4 + mi) * 2048;
            a[mi][0] = *(const bf16x8*)&lds[base + cb0];
            a[mi][1] = *(const bf16x8*)&lds[base + cb1];
        }
    };
    auto ldB = [&](int buf, int nh) {
        #pragma unroll
        for (int ni = 0; ni < 2; ++ni) {
            const int base = buf * 65536 + 32768 + bRow + (nh * 2 + ni) * 2048;
            b[nh * 2 + ni][0] = *(const bf16x8*)&lds[base + cb0];
            b[nh * 2 + ni][1] = *(const bf16x8*)&lds[base + cb1];
        }
    };
    auto mfmaQ = [&](int mlo, int nlo) {
        #pragma unroll
        for (int mi = 0; mi < 4; ++mi)
            #pragma unroll
            for (int ni = 0; ni < 2; ++ni)
                #pragma unroll
                for (int kk = 0; kk < 2; ++kk)
                    acc[mlo + mi][nlo + ni] = __builtin_amdgcn_mfma_f32_16x16x32_bf16(
                        a[mi][kk], b[nlo + ni][kk], acc[mlo + mi][nlo + ni], 0, 0, 0);
    };

    // ---- prologue: tile0 -> buf0, tile1.B -> buf1; vmcnt(4) keeps buf1.B in flight
    STG(Bsrc, 0, 0, BOFF0); STG(Bsrc, 1, 0, BOFF0);
    STG(Asrc, 0, 0, AOFF0); STG(Asrc, 1, 0, AOFF0);
    STG(Bsrc, 0, 1, BOFF1); STG(Bsrc, 1, 1, BOFF1);
    VMW4(); BARRIER();

    #pragma unroll 1
    for (int ki = 0; ki < NI; ++ki) {
        const int t1 = 2 * ki + 1;
        const int p0 = (2 * ki + 2) & (NT - 1);   // wrap on final iter: restages
        const int p1 = (2 * ki + 3) & (NT - 1);   // same data into dead buffers

        // P1: buf0 (m0-3, n0-1)
        ldA(0, 0); ldB(0, 0);
        STG(Asrc, 0, t1, AOFF1);
        BARRIER();
        PRIO1(); mfmaQ(0, 0); PRIO0();
        LGKM0(); BARRIER();

        // P2: buf0 (m0-3, n2-3)
        ldB(0, 1);
        STG(Asrc, 1, t1, AOFF1);
        BARRIER();
        PRIO1(); mfmaQ(0, 2); PRIO0();
        LGKM0(); BARRIER();

        // P3: buf0 (m4-7, n2-3)   [buf0.B dead after P2 -> safe to restage]
        ldA(0, 1);
        STG(Bsrc, 0, p0, BOFF0);
        BARRIER();
        PRIO1(); mfmaQ(4, 2); PRIO0();
        LGKM0(); BARRIER();

        // P4: buf0 (m4-7, n0-1); vmcnt gate for buf1 reads in P5
        STG(Bsrc, 1, p0, BOFF0);
        BARRIER();
        PRIO1(); mfmaQ(4, 0); PRIO0();
        VMW4(); BARRIER();

        // P5: buf1 (m0-3, n0-1)   [buf0.A dead after P3 -> safe to restage]
        ldA(1, 0); ldB(1, 0);
        STG(Asrc, 0, p0, AOFF0);
        BARRIER();
        PRIO1(); mfmaQ(0, 0); PRIO0();
        LGKM0(); BARRIER();

        // P6: buf1 (m0-3, n2-3)
        ldB(1, 1);
        STG(Asrc, 1, p0, AOFF0);
        BARRIER();
        PRIO1(); mfmaQ(0, 2); PRIO0();
        LGKM0(); BARRIER();

        // P7: buf1 (m4-7, n2-3)   [buf1.B dead after P6]
        ldA(1, 1);
        STG(Bsrc, 0, p1, BOFF1);
        BARRIER();
        PRIO1(); mfmaQ(4, 2); PRIO0();
        LGKM0(); BARRIER();

        // P8: buf1 (m4-7, n0-1); vmcnt gate for buf0 reads in next P1
        STG(Bsrc, 1, p1, BOFF1);
        BARRIER();
        PRIO1(); mfmaQ(4, 0); PRIO0();
        VMW4(); BARRIER();
    }
    VMW0();   // drain trailing (wrapped) stages before epilogue

#undef STG

    // ---- epilogue: C/D layout col = lane&15, row = quad*4 + reg  [m89] ----
    #pragma unroll
    for (int ni = 0; ni < 4; ++ni) {
        const int col = n0 + wn + ni * 16 + r15;
        if (col < Nout) {
            const float bv = bias[col];
            const bool is_sng = SNG && (col == 31 || col == 104 || col == 928);
            #pragma unroll
            for (int mi = 0; mi < 8; ++mi) {
                #pragma unroll
                for (int r = 0; r < 4; ++r) {
                    const int row = m0 + wm + mi * 16 + quad * 4 + r;
                    float v = acc[mi][ni][r] + bv;
                    if (ACT == 1) v = (v > 0.f) ? v : (fast_exp(v) - 1.f);
                    else if (ACT == 2) v = fast_rcp(1.f + fast_exp(-v));
                    store_val(C, (size_t)row * ldc + col, v);
                    if constexpr (SNG) {
                        if (is_sng) sngl[(size_t)row * 929 + col] = v;
                    }
                }
            }
        }
    }
}

// ---------------------------------------------------------------------------
// Gumbel-softmax epilogue v2: no LDS, register-resident y, 2 rows per wave.
//   y2 = (logit + g)/TEMP * log2(e)
//      = 1.8033688*logit - 1.25*log2(-ln2*log2(u+eps) + eps)    [ln2*log2e=1]
//   p  = 2^(y2 - max) / sum(2^(y2 - max))
// ---------------------------------------------------------------------------
#define NEG_BIG (-1e30f)
#define Y2_LG   1.8033688011f   // 1.25 * log2(e)

__device__ __forceinline__ float y2_col(const uint16_t* __restrict__ rlg,
                                        const float* __restrict__ ru, int c) {
    float l2u   = __builtin_amdgcn_logf(ru[c] + GEPS);   // log2(u+eps)
    float inner = fmaf(-LN2, l2u, GEPS);                 // -ln(u+eps)+eps
    float l2i   = __builtin_amdgcn_logf(inner);          // log2(inner)
    return fmaf(Y2_LG, bf2f(rlg[c]), -1.25f * l2i);
}

template<int N, int OFF>
__device__ __forceinline__ void seg_small(const uint16_t* __restrict__ rlg,
                                          const float* __restrict__ ru,
                                          float* __restrict__ rout, int l32) {
    static_assert(N <= 32, "seg_small needs N<=32");
    constexpr int GS = (N <= 2) ? 2 : (N <= 4) ? 4 : (N <= 8) ? 8 : (N <= 16) ? 16 : 32;
    const bool act = l32 < N;
    const int  c   = OFF + l32;
    float y = act ? y2_col(rlg, ru, c) : NEG_BIG;
    float m = y;
    #pragma unroll
    for (int o = 1; o < GS; o <<= 1) m = fmaxf(m, __shfl_xor(m, o, 64));
    float e = act ? fast_exp2(y - m) : 0.f;
    float s = e;
    #pragma unroll
    for (int o = 1; o < GS; o <<= 1) s += __shfl_xor(s, o, 64);
    if (act) rout[c] = e * fast_rcp(s);
}

template<int N, int OFF>
__device__ __forceinline__ void seg_wide(const uint16_t* __restrict__ rlg,
                                         const float* __restrict__ ru,
                                         float* __restrict__ rout, int lane) {
    constexpr int IT = (N + 63) / 64;
    float y[IT];
    float m = NEG_BIG;
    #pragma unroll
    for (int i = 0; i < IT; ++i) {
        const int j = i * 64 + lane;
        y[i] = (j < N) ? y2_col(rlg, ru, OFF + j) : NEG_BIG;
        m = fmaxf(m, y[i]);
    }
    #pragma unroll
    for (int o = 1; o < 64; o <<= 1) m = fmaxf(m, __shfl_xor(m, o, 64));
    float s = 0.f;
    #pragma unroll
    for (int i = 0; i < IT; ++i) {
        float e = fast_exp2(y[i] - m);   // inactive lanes: 2^(-1e30) = 0
        y[i] = e;
        s += e;
    }
    #pragma unroll
    for (int o = 1; o < 64; o <<= 1) s += __shfl_xor(s, o, 64);
    const float inv = fast_rcp(s);
    #pragma unroll
    for (int i = 0; i < IT; ++i) {
        const int j = i * 64 + lane;
        if (j < N) rout[OFF + j] = y[i] * inv;
    }
}

__global__ __launch_bounds__(256)
void gumbel_epilogue(const uint16_t* __restrict__ lg, float* __restrict__ out,
                     const float* __restrict__ u, int B) {
    const int wave = threadIdx.x >> 6, lane = threadIdx.x & 63;
    const int l32  = lane & 31, half = lane >> 5;
    const int rowA = blockIdx.x * 8 + wave * 2;
    if (rowA >= B) return;

    const size_t baseA = (size_t)rowA * 929;
    const size_t baseB = baseA + 929;
    const size_t baseH = half ? baseB : baseA;

    // paired small segments: each 32-lane half handles its own row
    const uint16_t* lgH = lg  + baseH;
    const float*    uH  = u   + baseH;
    float*          oH  = out + baseH;
    seg_small<29,   0>(lgH, uH, oH, l32);
    seg_small< 2,  29>(lgH, uH, oH, l32);
    seg_small< 6,  32>(lgH, uH, oH, l32);
    seg_small< 7,  38>(lgH, uH, oH, l32);
    seg_small<24, 105>(lgH, uH, oH, l32);
    seg_small< 3, 916>(lgH, uH, oH, l32);
    seg_small< 9, 919>(lgH, uH, oH, l32);

    // wide segments: full wave, one row at a time (independent -> ILP)
    const uint16_t* lgA = lg + baseA; const float* uA = u + baseA; float* oA = out + baseA;
    const uint16_t* lgB = lg + baseB; const float* uB = u + baseB; float* oB = out + baseB;
    seg_wide< 59,  45>(lgA, uA, oA, lane);
    seg_wide< 59,  45>(lgB, uB, oB, lane);
    seg_wide< 76, 129>(lgA, uA, oA, lane);
    seg_wide< 76, 129>(lgB, uB, oB, lane);
    seg_wide<711, 205>(lgA, uA, oA, lane);
    seg_wide<711, 205>(lgB, uB, oB, lane);
}

// ---------------------------------------------------------------------------
extern "C" void kernel_launch(void* const* d_in, const int* in_sizes, int n_in,
                              void* d_out, int out_size, void* d_ws, size_t ws_size,
                              hipStream_t stream) {
    const float* x  = (const float*)d_in[0];
    const float* W1 = (const float*)d_in[1];
    const float* b1 = (const float*)d_in[2];
    const float* W2 = (const float*)d_in[3];
    const float* b2 = (const float*)d_in[4];
    const float* W3 = (const float*)d_in[5];
    const float* b3 = (const float*)d_in[6];
    const float* u  = (const float*)d_in[7];
    float* out = (float*)d_out;

    const int B = 32768, D = 128, H = 1024, O = 929, OP = 1024;

    char* ws = (char*)d_ws;
    uint16_t* xb  = (uint16_t*)ws; ws += (size_t)B * D * 2;   // 8 MB
    uint16_t* w1t = (uint16_t*)ws; ws += (size_t)H * D * 2;   // 0.25 MB
    uint16_t* w2t = (uint16_t*)ws; ws += (size_t)H * H * 2;   // 2 MB
    uint16_t* w3t = (uint16_t*)ws; ws += (size_t)OP * H * 2;  // 2 MB
    uint16_t* h1  = (uint16_t*)ws; ws += (size_t)B * H * 2;   // 64 MB
    uint16_t* h2  = (uint16_t*)ws; ws += (size_t)B * H * 2;   // 64 MB
    // logits (bf16, B x 929 = 61 MB) alias the h1 buffer — h1 is dead after GEMM2
    uint16_t* lg  = h1;

    cast_bf16<<<(B * D / 4 + 255) / 256, 256, 0, stream>>>(x, xb, B * D);
    transpose_cast<<<dim3(H / 64, D / 64), 256, 0, stream>>>(W1, w1t, D, H, H);
    transpose_cast<<<dim3(H / 64, H / 64), 256, 0, stream>>>(W2, w2t, H, H, H);
    transpose_cast<<<dim3(OP / 64, H / 64), 256, 0, stream>>>(W3, w3t, H, O, OP);

    // h1 = elu(x @ W1 + b1)   (K=128: known-good 128x128 kernel)
    gemm_bt<1, uint16_t, false><<<dim3(H / 128, B / 128), 256, 0, stream>>>(
        xb, w1t, b1, h1, nullptr, D, H, H);
    // h2 = sigmoid(h1 @ W2 + b2)   (Nout = ldc = H)
    gemm256<2, uint16_t, false, 1024><<<dim3(H / 256, B / 256), 512, 0, stream>>>(
        h1, w2t, b2, h2, nullptr, H, H);
    // logits -> bf16 ws buffer; fp32 singleton cols (31,104,928) -> d_out
    gemm256<0, uint16_t, true, 1024><<<dim3(OP / 256, B / 256), 512, 0, stream>>>(
        h2, w3t, b3, lg, out, O, O);

    // gumbel softmax: bf16 logits -> fp32 out (singletons already final)
    gumbel_epilogue<<<B / 8, 256, 0, stream>>>(lg, out, u, B);
}

// Round 8
// 463.745 us; speedup vs baseline: 1.1685x; 1.0453x over previous
//
#include <hip/hip_runtime.h>
#include <hip/hip_bf16.h>
#include <stdint.h>

#define GEPS 1e-20f

typedef __bf16 bf16x8 __attribute__((ext_vector_type(8)));
typedef float  f32x4  __attribute__((ext_vector_type(4)));

typedef const __attribute__((address_space(1))) uint32_t* gptr32;
typedef __attribute__((address_space(3))) uint32_t* lptr32;

__device__ __forceinline__ void load_lds16(const void* g, void* l) {
    __builtin_amdgcn_global_load_lds((gptr32)g, (lptr32)l, 16, 0, 0);
}

__device__ __forceinline__ uint16_t f2bf(float v) {
    __hip_bfloat16 b = __float2bfloat16(v);
    return *(uint16_t*)&b;
}
__device__ __forceinline__ float bf2f(uint16_t b) {
    uint32_t u = (uint32_t)b << 16;
    return __builtin_bit_cast(float, u);
}

// hardware transcendentals: v_log_f32 = log2(x), v_exp_f32 = 2^x  (~1 ULP)
#define LN2   0.69314718056f
#define LOG2E 1.44269504089f
__device__ __forceinline__ float fast_log(float x) { return __builtin_amdgcn_logf(x) * LN2; }
__device__ __forceinline__ float fast_exp(float x) { return __builtin_amdgcn_exp2f(x * LOG2E); }
__device__ __forceinline__ float fast_exp2(float x) { return __builtin_amdgcn_exp2f(x); }
__device__ __forceinline__ float fast_rcp(float x)  { return __builtin_amdgcn_rcpf(x); }

__device__ __forceinline__ void store_val(uint16_t* C, size_t idx, float v) { C[idx] = f2bf(v); }
__device__ __forceinline__ void store_val(float* C, size_t idx, float v)    { C[idx] = v; }

// ---------------------------------------------------------------------------
// cast fp32 -> bf16, vectorized (n must be multiple of 4)
// ---------------------------------------------------------------------------
__global__ void cast_bf16(const float* __restrict__ in, uint16_t* __restrict__ out, int n) {
    int i = (blockIdx.x * blockDim.x + threadIdx.x) * 4;
    if (i < n) {
        float4 v = *(const float4*)(in + i);
        ushort4 o;
        o.x = f2bf(v.x); o.y = f2bf(v.y); o.z = f2bf(v.z); o.w = f2bf(v.w);
        *(ushort4*)(out + i) = o;
    }
}

// ---------------------------------------------------------------------------
// W (K x N, fp32, row-major) -> Wt (Npad x K, bf16, row-major), zero-pad n>=N
// ---------------------------------------------------------------------------
__global__ void transpose_cast(const float* __restrict__ W, uint16_t* __restrict__ Wt,
                               int K, int N, int Npad) {
    __shared__ float tile[64][65];
    const int k0 = blockIdx.y * 64, n0 = blockIdx.x * 64;
    const int tx = threadIdx.x & 63, ty = threadIdx.x >> 6;
    for (int r = ty; r < 64; r += 4) {
        int n = n0 + tx;
        tile[r][tx] = (n < N) ? W[(size_t)(k0 + r) * N + n] : 0.f;
    }
    __syncthreads();
    for (int r = ty; r < 64; r += 4) {
        Wt[(size_t)(n0 + r) * K + k0 + tx] = f2bf(tile[tx][r]);
    }
}

// ---------------------------------------------------------------------------
// KNOWN-GOOD 128x128 GEMM (verified rounds 0-1): C = act(A @ Bt^T + bias)
// Used for GEMM1 (K=128) where the deep pipeline doesn't pay anyway.
// ---------------------------------------------------------------------------
template<int ACT, typename OutT, bool SNG>
__global__ __launch_bounds__(256)
void gemm_bt(const uint16_t* __restrict__ A, const uint16_t* __restrict__ Bt,
             const float* __restrict__ bias, OutT* __restrict__ C,
             float* __restrict__ sngl,
             int K, int Nout, int ldc) {
    __shared__ __align__(16) uint16_t As[128 * 32];
    __shared__ __align__(16) uint16_t Bs[128 * 32];

    const int t    = threadIdx.x;
    const int wave = t >> 6, lane = t & 63;

    const int nbx = gridDim.x;
    const int bid = blockIdx.y * nbx + blockIdx.x;
    const int xcd = bid & 7;
    const int s   = bid >> 3;
    const int nidx = s % nbx;
    const int midx = xcd * (gridDim.y >> 3) + s / nbx;

    const int m0 = midx * 128, n0 = nidx * 128;
    const int wm = (wave >> 1) * 64, wn = (wave & 1) * 64;
    const int quad = lane >> 4;
    const int qk   = quad * 8;
    const int r15  = lane & 15;

    f32x4 acc[4][4] = {};

    const uint16_t* Ag = A  + (size_t)m0 * K;
    const uint16_t* Bg = Bt + (size_t)n0 * K;

    for (int k0 = 0; k0 < K; k0 += 32) {
        __syncthreads();
        #pragma unroll
        for (int rd = 0; rd < 2; ++rd) {
            int c = t + rd * 256;            // 16B-chunk index, 0..511
            int row = c >> 2, kc = (c & 3) * 8;
            load_lds16(Ag + (size_t)row * K + k0 + kc, &As[c * 8]);
            load_lds16(Bg + (size_t)row * K + k0 + kc, &Bs[c * 8]);
        }
        __syncthreads();

        bf16x8 a[4], b[4];
        #pragma unroll
        for (int i = 0; i < 4; ++i)
            a[i] = *(const bf16x8*)&As[(wm + i * 16 + r15) * 32 + qk];
        #pragma unroll
        for (int i = 0; i < 4; ++i)
            b[i] = *(const bf16x8*)&Bs[(wn + i * 16 + r15) * 32 + qk];

        #pragma unroll
        for (int mi = 0; mi < 4; ++mi)
            #pragma unroll
            for (int ni = 0; ni < 4; ++ni)
                acc[mi][ni] = __builtin_amdgcn_mfma_f32_16x16x32_bf16(
                    a[mi], b[ni], acc[mi][ni], 0, 0, 0);
    }

    #pragma unroll
    for (int ni = 0; ni < 4; ++ni) {
        int col = n0 + wn + ni * 16 + r15;
        if (col < Nout) {
            float bv = bias[col];
            bool is_sng = SNG && (col == 31 || col == 104 || col == 928);
            #pragma unroll
            for (int mi = 0; mi < 4; ++mi) {
                #pragma unroll
                for (int r = 0; r < 4; ++r) {
                    int row = m0 + wm + mi * 16 + quad * 4 + r;
                    float v = acc[mi][ni][r] + bv;
                    if (ACT == 1) v = (v > 0.f) ? v : (fast_exp(v) - 1.f);
                    else if (ACT == 2) v = fast_rcp(1.f + fast_exp(-v));
                    store_val(C, (size_t)row * ldc + col, v);
                    if constexpr (SNG) {
                        if (is_sng) sngl[(size_t)row * 929 + col] = v;
                    }
                }
            }
        }
    }
}

// ---------------------------------------------------------------------------
// 256x256 8-phase GEMM, v3:  C = act(A @ Bt^T + bias)
//  (1) DEEP PREFETCH: stages only in P3/P4/P7/P8 (4 loads each), gates
//      vmcnt(8) at P4/P8. Stage->gate distance = 4 phases (~1600 cyc) >
//      HBM latency (~900). Ledger (FIFO): prologue 16 loads + vmcnt(8);
//      at each gate 16 outstanding -> retire oldest 8 = exactly the buffer
//      pair read next, leave newest 8 in flight.
//  (2) LDS-STAGED EPILOGUE: K-loop LDS is dead after VMW0+barrier. Write
//      acc as bf16 into swizzled [256][256] (byte ^= (row&7)<<4), barrier,
//      read back 16B chunks (32 lanes = one full 512B row) -> coalesced
//      dwordx4 stores, exact-size HBM writes. Requires 16B-aligned rows ->
//      logits use ldc=1024 (padded).
// ---------------------------------------------------------------------------
#define BARRIER() asm volatile("s_barrier" ::: "memory")
#define LGKM0()   asm volatile("s_waitcnt lgkmcnt(0)" ::: "memory")
#define VMW8()    asm volatile("s_waitcnt vmcnt(8)" ::: "memory")
#define VMW0()    asm volatile("s_waitcnt vmcnt(0)" ::: "memory")
#define PRIO1()   __builtin_amdgcn_s_setprio(1)
#define PRIO0()   __builtin_amdgcn_s_setprio(0)

template<int ACT, typename OutT, bool SNG, int K>
__global__ __launch_bounds__(512, 2)
void gemm256(const uint16_t* __restrict__ A, const uint16_t* __restrict__ Bt,
             const float* __restrict__ bias, OutT* __restrict__ C,
             float* __restrict__ sngl, int Nout, int ldc) {
    constexpr int NT = K / 64;           // K-tiles
    constexpr int NI = NT / 2;           // iterations (2 K-tiles each)
    constexpr int KB = K * 2;            // global row stride, bytes
    __shared__ __align__(16) char lds[131072];
    constexpr int AOFF0 = 0, BOFF0 = 32768, AOFF1 = 65536, BOFF1 = 98304;

    const int t = threadIdx.x;
    const int wave = t >> 6, lane = t & 63;
    const int quad = lane >> 4, r15 = lane & 15;
    const int wm = (wave >> 2) * 128, wn = (wave & 3) * 64;

    // ---- XCD-aware block remap (gridDim.y divisible by 8) ----
    const int nbx = gridDim.x;
    const int bid = blockIdx.y * nbx + blockIdx.x;
    const int xcd = bid & 7;
    const int sb  = bid >> 3;
    const int nidx = sb % nbx;
    const int midx = xcd * (gridDim.y >> 3) + sb / nbx;
    const int m0 = midx * 256, n0 = nidx * 256;

    // ---- staging addresses ----
    const int srow = t >> 3;                          // 0..63
    const int scb  = ((t & 7) ^ (srow & 7)) << 4;     // inverse-swizzled src col byte
    const char* Asrc = (const char*)A  + (size_t)(m0 + srow) * KB + scb;
    const char* Bsrc = (const char*)Bt + (size_t)(n0 + srow) * KB + scb;

    // ---- LDS read addressing (swizzled) ----
    const int sx   = (r15 & 7) << 4;
    const int cb0  = (quad * 16) ^ sx;        // kk = 0: chunk quad
    const int cb1  = (64 + quad * 16) ^ sx;   // kk = 1: chunk 4+quad
    const int aRow = (wm + r15) * 128;
    const int bRow = (wn + r15) * 128;

    f32x4 acc[8][4] = {};
    bf16x8 a[4][2], b[4][2];

#define STG(src, half, tile, ldsOff)                                                      \
    do {                                                                                  \
        const char* _s = (src) + (size_t)((half) * 128) * KB + (size_t)(tile) * 128;      \
        load_lds16(_s,                   &lds[(ldsOff) + (half) * 16384 + t * 16]);       \
        load_lds16(_s + (size_t)64 * KB, &lds[(ldsOff) + (half) * 16384 + 8192 + t * 16]);\
    } while (0)

    auto ldA = [&](int buf, int mh) {
        #pragma unroll
        for (int mi = 0; mi < 4; ++mi) {
            const int base = buf * 65536 + aRow + (mh * 4 + mi) * 2048;
            a[mi][0] = *(const bf16x8*)&lds[base + cb0];
            a[mi][1] = *(const bf16x8*)&lds[base + cb1];
        }
    };
    auto ldB = [&](int buf, int nh) {
        #pragma unroll
        for (int ni = 0; ni < 2; ++ni) {
            const int base = buf * 65536 + 32768 + bRow + (nh * 2 + ni) * 2048;
            b[nh * 2 + ni][0] = *(const bf16x8*)&lds[base + cb0];
            b[nh * 2 + ni][1] = *(const bf16x8*)&lds[base + cb1];
        }
    };
    auto mfmaQ = [&](int mlo, int nlo) {
        #pragma unroll
        for (int mi = 0; mi < 4; ++mi)
            #pragma unroll
            for (int ni = 0; ni < 2; ++ni)
                #pragma unroll
                for (int kk = 0; kk < 2; ++kk)
                    acc[mlo + mi][nlo + ni] = __builtin_amdgcn_mfma_f32_16x16x32_bf16(
                        a[mi][kk], b[nlo + ni][kk], acc[mlo + mi][nlo + ni], 0, 0, 0);
    };

    // ---- prologue: both K-tiles fully staged; vmcnt(8) completes buf0,
    //      leaves buf1's 8 loads in flight (gated at first P4) ----
    STG(Bsrc, 0, 0, BOFF0); STG(Bsrc, 1, 0, BOFF0);
    STG(Asrc, 0, 0, AOFF0); STG(Asrc, 1, 0, AOFF0);
    STG(Bsrc, 0, 1, BOFF1); STG(Bsrc, 1, 1, BOFF1);
    STG(Asrc, 0, 1, AOFF1); STG(Asrc, 1, 1, AOFF1);
    VMW8(); BARRIER();

    #pragma unroll 1
    for (int ki = 0; ki < NI; ++ki) {
        const int p0 = (2 * ki + 2) & (NT - 1);   // wrap on final iter: restages
        const int p1 = (2 * ki + 3) & (NT - 1);   // same data into dead buffers

        // P1: buf0 (m0-3, n0-1)
        ldA(0, 0); ldB(0, 0);
        BARRIER();
        PRIO1(); mfmaQ(0, 0); PRIO0();
        LGKM0(); BARRIER();

        // P2: buf0 (m0-3, n2-3)
        ldB(0, 1);
        BARRIER();
        PRIO1(); mfmaQ(0, 2); PRIO0();
        LGKM0(); BARRIER();

        // P3: buf0 (m4-7, n2-3); stage buf0.B <- p0  [buf0.B last read P2]
        ldA(0, 1);
        STG(Bsrc, 0, p0, BOFF0); STG(Bsrc, 1, p0, BOFF0);
        BARRIER();
        PRIO1(); mfmaQ(4, 2); PRIO0();
        LGKM0(); BARRIER();

        // P4: buf0 (m4-7, n0-1); stage buf0.A <- p0  [buf0.A last read P3]
        // GATE vmcnt(8): retires prev buf1.B + buf1.A (issued 4 phases ago)
        STG(Asrc, 0, p0, AOFF0); STG(Asrc, 1, p0, AOFF0);
        BARRIER();
        PRIO1(); mfmaQ(4, 0); PRIO0();
        VMW8(); BARRIER();

        // P5: buf1 (m0-3, n0-1)
        ldA(1, 0); ldB(1, 0);
        BARRIER();
        PRIO1(); mfmaQ(0, 0); PRIO0();
        LGKM0(); BARRIER();

        // P6: buf1 (m0-3, n2-3)
        ldB(1, 1);
        BARRIER();
        PRIO1(); mfmaQ(0, 2); PRIO0();
        LGKM0(); BARRIER();

        // P7: buf1 (m4-7, n2-3); stage buf1.B <- p1  [buf1.B last read P6]
        ldA(1, 1);
        STG(Bsrc, 0, p1, BOFF1); STG(Bsrc, 1, p1, BOFF1);
        BARRIER();
        PRIO1(); mfmaQ(4, 2); PRIO0();
        LGKM0(); BARRIER();

        // P8: buf1 (m4-7, n0-1); stage buf1.A <- p1  [buf1.A last read P7]
        // GATE vmcnt(8): retires P3+P4 stages (buf0 next tile)
        STG(Asrc, 0, p1, AOFF1); STG(Asrc, 1, p1, AOFF1);
        BARRIER();
        PRIO1(); mfmaQ(4, 0); PRIO0();
        VMW8(); BARRIER();
    }
    VMW0();     // drain trailing (wrapped) stages before LDS reuse
    BARRIER();

#undef STG

    // ---- epilogue v2: LDS-staged coalesced store ----
    // write phase: acc -> bf16 into swizzled [256][256] tile (row*512 bytes,
    // 16B-chunk XOR (row&7)<<4). C/D layout: col=lane&15, row=quad*4+reg [m89]
    #pragma unroll
    for (int ni = 0; ni < 4; ++ni) {
        const int col = wn + ni * 16 + r15;      // tile-local col
        const int gc  = n0 + col;                // global col
        const float bv = (gc < Nout) ? bias[gc] : 0.f;
        const bool is_sng = SNG && (gc == 31 || gc == 104 || gc == 928);
        #pragma unroll
        for (int mi = 0; mi < 8; ++mi) {
            #pragma unroll
            for (int r = 0; r < 4; ++r) {
                const int row = wm + mi * 16 + quad * 4 + r;   // tile-local row
                float v = acc[mi][ni][r] + bv;
                if (ACT == 1) v = (v > 0.f) ? v : (fast_exp(v) - 1.f);
                else if (ACT == 2) v = fast_rcp(1.f + fast_exp(-v));
                *(uint16_t*)&lds[row * 512 + ((col * 2) ^ ((row & 7) << 4))] = f2bf(v);
                if constexpr (SNG) {
                    if (is_sng) sngl[(size_t)(m0 + row) * 929 + gc] = v;
                }
            }
        }
    }
    LGKM0(); BARRIER();

    // read-back: 32 lanes cover one full 512B row -> 16B coalesced stores.
    // ldc*2 must be 16B-aligned (ldc=1024 everywhere gemm256 is used).
    {
        const int rt = t >> 5;          // 0..15: row-in-pass
        const int cc = t & 31;          // 0..31: 16B chunk in row
        #pragma unroll 1
        for (int pass = 0; pass < 16; ++pass) {
            const int row = pass * 16 + rt;
            f32x4 v4 = *(const f32x4*)&lds[row * 512 + ((cc * 16) ^ ((row & 7) << 4))];
            *(f32x4*)&C[(size_t)(m0 + row) * ldc + n0 + cc * 8] = v4;
        }
    }
}

// ---------------------------------------------------------------------------
// Gumbel-softmax epilogue v2: no LDS, register-resident y, 2 rows per wave.
//   y2 = (logit + g)/TEMP * log2(e)
//      = 1.8033688*logit - 1.25*log2(-ln2*log2(u+eps) + eps)    [ln2*log2e=1]
//   p  = 2^(y2 - max) / sum(2^(y2 - max))
// NOTE: logits buffer lg is PADDED to stride 1024; u/out remain stride 929.
// Cols 929..1023 of lg are garbage and never read.
// ---------------------------------------------------------------------------
#define NEG_BIG (-1e30f)
#define Y2_LG   1.8033688011f   // 1.25 * log2(e)

__device__ __forceinline__ float y2_col(const uint16_t* __restrict__ rlg,
                                        const float* __restrict__ ru, int c) {
    float l2u   = __builtin_amdgcn_logf(ru[c] + GEPS);   // log2(u+eps)
    float inner = fmaf(-LN2, l2u, GEPS);                 // -ln(u+eps)+eps
    float l2i   = __builtin_amdgcn_logf(inner);          // log2(inner)
    return fmaf(Y2_LG, bf2f(rlg[c]), -1.25f * l2i);
}

template<int N, int OFF>
__device__ __forceinline__ void seg_small(const uint16_t* __restrict__ rlg,
                                          const float* __restrict__ ru,
                                          float* __restrict__ rout, int l32) {
    static_assert(N <= 32, "seg_small needs N<=32");
    constexpr int GS = (N <= 2) ? 2 : (N <= 4) ? 4 : (N <= 8) ? 8 : (N <= 16) ? 16 : 32;
    const bool act = l32 < N;
    const int  c   = OFF + l32;
    float y = act ? y2_col(rlg, ru, c) : NEG_BIG;
    float m = y;
    #pragma unroll
    for (int o = 1; o < GS; o <<= 1) m = fmaxf(m, __shfl_xor(m, o, 64));
    float e = act ? fast_exp2(y - m) : 0.f;
    float s = e;
    #pragma unroll
    for (int o = 1; o < GS; o <<= 1) s += __shfl_xor(s, o, 64);
    if (act) rout[c] = e * fast_rcp(s);
}

template<int N, int OFF>
__device__ __forceinline__ void seg_wide(const uint16_t* __restrict__ rlg,
                                         const float* __restrict__ ru,
                                         float* __restrict__ rout, int lane) {
    constexpr int IT = (N + 63) / 64;
    float y[IT];
    float m = NEG_BIG;
    #pragma unroll
    for (int i = 0; i < IT; ++i) {
        const int j = i * 64 + lane;
        y[i] = (j < N) ? y2_col(rlg, ru, OFF + j) : NEG_BIG;
        m = fmaxf(m, y[i]);
    }
    #pragma unroll
    for (int o = 1; o < 64; o <<= 1) m = fmaxf(m, __shfl_xor(m, o, 64));
    float s = 0.f;
    #pragma unroll
    for (int i = 0; i < IT; ++i) {
        float e = fast_exp2(y[i] - m);   // inactive lanes: 2^(-1e30) = 0
        y[i] = e;
        s += e;
    }
    #pragma unroll
    for (int o = 1; o < 64; o <<= 1) s += __shfl_xor(s, o, 64);
    const float inv = fast_rcp(s);
    #pragma unroll
    for (int i = 0; i < IT; ++i) {
        const int j = i * 64 + lane;
        if (j < N) rout[OFF + j] = y[i] * inv;
    }
}

__global__ __launch_bounds__(256)
void gumbel_epilogue(const uint16_t* __restrict__ lg, float* __restrict__ out,
                     const float* __restrict__ u, int B) {
    const int wave = threadIdx.x >> 6, lane = threadIdx.x & 63;
    const int l32  = lane & 31, half = lane >> 5;
    const int rowA = blockIdx.x * 8 + wave * 2;
    if (rowA >= B) return;

    const size_t uoA  = (size_t)rowA * 929;        // u / out stride 929
    const size_t uoB  = uoA + 929;
    const size_t lgoA = (size_t)rowA * 1024;       // lg stride 1024 (padded)
    const size_t lgoB = lgoA + 1024;
    const size_t uoH  = half ? uoB  : uoA;
    const size_t lgoH = half ? lgoB : lgoA;

    // paired small segments: each 32-lane half handles its own row
    const uint16_t* lgH = lg  + lgoH;
    const float*    uH  = u   + uoH;
    float*          oH  = out + uoH;
    seg_small<29,   0>(lgH, uH, oH, l32);
    seg_small< 2,  29>(lgH, uH, oH, l32);
    seg_small< 6,  32>(lgH, uH, oH, l32);
    seg_small< 7,  38>(lgH, uH, oH, l32);
    seg_small<24, 105>(lgH, uH, oH, l32);
    seg_small< 3, 916>(lgH, uH, oH, l32);
    seg_small< 9, 919>(lgH, uH, oH, l32);

    // wide segments: full wave, one row at a time (independent -> ILP)
    const uint16_t* lgA = lg + lgoA; const float* uA = u + uoA; float* oA = out + uoA;
    const uint16_t* lgB = lg + lgoB; const float* uB = u + uoB; float* oB = out + uoB;
    seg_wide< 59,  45>(lgA, uA, oA, lane);
    seg_wide< 59,  45>(lgB, uB, oB, lane);
    seg_wide< 76, 129>(lgA, uA, oA, lane);
    seg_wide< 76, 129>(lgB, uB, oB, lane);
    seg_wide<711, 205>(lgA, uA, oA, lane);
    seg_wide<711, 205>(lgB, uB, oB, lane);
}

// ---------------------------------------------------------------------------
extern "C" void kernel_launch(void* const* d_in, const int* in_sizes, int n_in,
                              void* d_out, int out_size, void* d_ws, size_t ws_size,
                              hipStream_t stream) {
    const float* x  = (const float*)d_in[0];
    const float* W1 = (const float*)d_in[1];
    const float* b1 = (const float*)d_in[2];
    const float* W2 = (const float*)d_in[3];
    const float* b2 = (const float*)d_in[4];
    const float* W3 = (const float*)d_in[5];
    const float* b3 = (const float*)d_in[6];
    const float* u  = (const float*)d_in[7];
    float* out = (float*)d_out;

    const int B = 32768, D = 128, H = 1024, O = 929, OP = 1024;

    char* ws = (char*)d_ws;
    uint16_t* xb  = (uint16_t*)ws; ws += (size_t)B * D * 2;   // 8 MB
    uint16_t* w1t = (uint16_t*)ws; ws += (size_t)H * D * 2;   // 0.25 MB
    uint16_t* w2t = (uint16_t*)ws; ws += (size_t)H * H * 2;   // 2 MB
    uint16_t* w3t = (uint16_t*)ws; ws += (size_t)OP * H * 2;  // 2 MB
    uint16_t* h1  = (uint16_t*)ws; ws += (size_t)B * H * 2;   // 64 MB
    uint16_t* h2  = (uint16_t*)ws; ws += (size_t)B * H * 2;   // 64 MB
    // logits (bf16, B x 1024 padded = 64 MB) alias h1 — h1 dead after GEMM2
    uint16_t* lg  = h1;

    cast_bf16<<<(B * D / 4 + 255) / 256, 256, 0, stream>>>(x, xb, B * D);
    transpose_cast<<<dim3(H / 64, D / 64), 256, 0, stream>>>(W1, w1t, D, H, H);
    transpose_cast<<<dim3(H / 64, H / 64), 256, 0, stream>>>(W2, w2t, H, H, H);
    transpose_cast<<<dim3(OP / 64, H / 64), 256, 0, stream>>>(W3, w3t, H, O, OP);

    // h1 = elu(x @ W1 + b1)   (K=128: known-good 128x128 kernel)
    gemm_bt<1, uint16_t, false><<<dim3(H / 128, B / 128), 256, 0, stream>>>(
        xb, w1t, b1, h1, nullptr, D, H, H);
    // h2 = sigmoid(h1 @ W2 + b2)   (Nout = ldc = H)
    gemm256<2, uint16_t, false, 1024><<<dim3(H / 256, B / 256), 512, 0, stream>>>(
        h1, w2t, b2, h2, nullptr, H, H);
    // logits -> padded bf16 buffer (ldc=1024); fp32 singletons -> d_out
    gemm256<0, uint16_t, true, 1024><<<dim3(OP / 256, B / 256), 512, 0, stream>>>(
        h2, w3t, b3, lg, out, O, 1024);

    // gumbel softmax: bf16 logits (stride 1024) -> fp32 out (stride 929)
    gumbel_epilogue<<<B / 8, 256, 0, stream>>>(lg, out, u, B);
}